// Round 1
// baseline (921.603 us; speedup 1.0000x reference)
//
#include <hip/hip_runtime.h>

#define RES 256
#define FEAT 32
#define PLANE_ELEMS (FEAT * RES * RES)   // 2097152 floats, 8 MB

// 13 sample offsets: (0,0) then the 12 OFFSETS from the reference.
__device__ __constant__ float c_offx[13] = {0.0f, -1.0f, -0.5f, 0.5f, 1.0f, 0.0f, 0.0f, 0.0f, 0.0f, 0.5f, 0.5f, -0.5f, -0.5f};
__device__ __constant__ float c_offy[13] = {0.0f, 0.0f, 0.0f, 0.0f, 0.0f, -1.0f, -0.5f, 0.5f, 1.0f, 0.5f, -0.5f, 0.5f, -0.5f};

// Transpose one plane (C,H,W) -> (H,W,C). One thread per output element.
__global__ __launch_bounds__(256) void transpose_plane(const float* __restrict__ in,
                                                       float* __restrict__ outp) {
    int t = blockIdx.x * 256 + threadIdx.x;   // t < 32*256*256
    int c = t & 31;
    int x = (t >> 5) & 255;
    int y = t >> 13;
    outp[t] = in[c * (RES * RES) + y * RES + x];
}

template <bool TRANSPOSED>
__device__ inline float4 fetch_corner(const float* __restrict__ plane, int y, int x, int cg) {
    if (TRANSPOSED) {
        const float4* p = reinterpret_cast<const float4*>(plane + ((size_t)(y * RES + x) << 5));
        return p[cg];
    } else {
        int base = y * RES + x;
        int c0 = cg << 2;
        float4 r;
        r.x = plane[(size_t)(c0 + 0) * (RES * RES) + base];
        r.y = plane[(size_t)(c0 + 1) * (RES * RES) + base];
        r.z = plane[(size_t)(c0 + 2) * (RES * RES) + base];
        r.w = plane[(size_t)(c0 + 3) * (RES * RES) + base];
        return r;
    }
}

template <bool TRANSPOSED>
__device__ inline void accum_pair(float4& interp, const float* __restrict__ plane,
                                  float bx, float by, float sx, float sy, int cg) {
    float4 featsum = make_float4(0.f, 0.f, 0.f, 0.f);
#pragma unroll
    for (int s = 0; s < 13; ++s) {
        float pxn = bx + sx * c_offx[s];
        float pyn = by + sy * c_offy[s];
        // x = clip((px+1)*0.5*(W-1), 0, W-1)
        float x = fminf(fmaxf((pxn + 1.0f) * 0.5f * 255.0f, 0.0f), 255.0f);
        float y = fminf(fmaxf((pyn + 1.0f) * 0.5f * 255.0f, 0.0f), 255.0f);
        float x0f = floorf(x);
        float y0f = floorf(y);
        float wx = x - x0f;
        float wy = y - y0f;
        int x0 = (int)x0f;
        int y0 = (int)y0f;
        int x1 = min(x0 + 1, RES - 1);
        int y1 = min(y0 + 1, RES - 1);
        float w00 = (1.0f - wx) * (1.0f - wy);
        float w10 = wx * (1.0f - wy);
        float w01 = (1.0f - wx) * wy;
        float w11 = wx * wy;
        float4 f00 = fetch_corner<TRANSPOSED>(plane, y0, x0, cg);
        float4 f10 = fetch_corner<TRANSPOSED>(plane, y0, x1, cg);
        float4 f01 = fetch_corner<TRANSPOSED>(plane, y1, x0, cg);
        float4 f11 = fetch_corner<TRANSPOSED>(plane, y1, x1, cg);
        featsum.x = fmaf(f00.x, w00, fmaf(f10.x, w10, fmaf(f01.x, w01, fmaf(f11.x, w11, featsum.x))));
        featsum.y = fmaf(f00.y, w00, fmaf(f10.y, w10, fmaf(f01.y, w01, fmaf(f11.y, w11, featsum.y))));
        featsum.z = fmaf(f00.z, w00, fmaf(f10.z, w10, fmaf(f01.z, w01, fmaf(f11.z, w11, featsum.z))));
        featsum.w = fmaf(f00.w, w00, fmaf(f10.w, w10, fmaf(f01.w, w01, fmaf(f11.w, w11, featsum.w))));
    }
    const float inv13 = 1.0f / 13.0f;
    interp.x *= featsum.x * inv13;
    interp.y *= featsum.y * inv13;
    interp.z *= featsum.z * inv13;
    interp.w *= featsum.w * inv13;
}

template <bool TRANSPOSED>
__global__ __launch_bounds__(256) void wpf_main(const float* __restrict__ pts,
                                                const float* __restrict__ scales,
                                                const float* __restrict__ p0,
                                                const float* __restrict__ p1,
                                                const float* __restrict__ p2,
                                                const float* __restrict__ aabb,
                                                float* __restrict__ out, int n) {
    int t = blockIdx.x * 256 + threadIdx.x;
    int pt = t >> 3;       // point index
    int cg = t & 7;        // channel group (4 channels each)
    if (pt >= n) return;

    // aabb row0 = max-corner-ish [BOUNDS]*3, row1 = [-BOUNDS]*3
    float a00 = aabb[0], a01 = aabb[1], a02 = aabb[2];
    float a10 = aabb[3], a11 = aabb[4], a12 = aabb[5];
    float s0 = 2.0f / (a10 - a00);
    float s1 = 2.0f / (a11 - a01);
    float s2 = 2.0f / (a12 - a02);

    float px = (pts[pt * 3 + 0] - a00) * s0 - 1.0f;
    float py = (pts[pt * 3 + 1] - a01) * s1 - 1.0f;
    float pz = (pts[pt * 3 + 2] - a02) * s2 - 1.0f;

    float scx = scales[pt * 3 + 0];
    float scy = scales[pt * 3 + 1];
    float scz = scales[pt * 3 + 2];

    float4 interp = make_float4(1.f, 1.f, 1.f, 1.f);
    // pair (0,1) -> plane0 : x-coord = dim0, y-coord = dim1
    accum_pair<TRANSPOSED>(interp, p0, px, py, scx, scy, cg);
    // pair (0,2) -> plane1
    accum_pair<TRANSPOSED>(interp, p1, px, pz, scx, scz, cg);
    // pair (1,2) -> plane2
    accum_pair<TRANSPOSED>(interp, p2, py, pz, scy, scz, cg);

    reinterpret_cast<float4*>(out)[(size_t)pt * 8 + cg] = interp;
}

extern "C" void kernel_launch(void* const* d_in, const int* in_sizes, int n_in,
                              void* d_out, int out_size, void* d_ws, size_t ws_size,
                              hipStream_t stream) {
    const float* pts    = (const float*)d_in[0];
    // d_in[1] = timestamps, unused by reference
    const float* scales = (const float*)d_in[2];
    const float* p0     = (const float*)d_in[3];
    const float* p1     = (const float*)d_in[4];
    const float* p2     = (const float*)d_in[5];
    const float* aabb   = (const float*)d_in[6];
    float* out = (float*)d_out;

    int n = in_sizes[0] / 3;
    int main_blocks = (n * 8 + 255) / 256;

    size_t need = (size_t)3 * PLANE_ELEMS * sizeof(float);
    if (ws_size >= need) {
        float* w0 = (float*)d_ws;
        float* w1 = w0 + PLANE_ELEMS;
        float* w2 = w1 + PLANE_ELEMS;
        int tb = PLANE_ELEMS / 256;
        transpose_plane<<<tb, 256, 0, stream>>>(p0, w0);
        transpose_plane<<<tb, 256, 0, stream>>>(p1, w1);
        transpose_plane<<<tb, 256, 0, stream>>>(p2, w2);
        wpf_main<true><<<main_blocks, 256, 0, stream>>>(pts, scales, w0, w1, w2, aabb, out, n);
    } else {
        wpf_main<false><<<main_blocks, 256, 0, stream>>>(pts, scales, p0, p1, p2, aabb, out, n);
    }
}

// Round 2
// 507.401 us; speedup vs baseline: 1.8163x; 1.8163x over previous
//
#include <hip/hip_runtime.h>

#define RES 256
#define FEAT 32
#define PLANE_ELEMS (FEAT * RES * RES)   // 2097152 floats, 8 MB
#define NBINS 32768                      // 32^3 Morton bins

// 13 sample offsets: (0,0) then the 12 OFFSETS from the reference.
__device__ __constant__ float c_offx[13] = {0.0f, -1.0f, -0.5f, 0.5f, 1.0f, 0.0f, 0.0f, 0.0f, 0.0f, 0.5f, 0.5f, -0.5f, -0.5f};
__device__ __constant__ float c_offy[13] = {0.0f, 0.0f, 0.0f, 0.0f, 0.0f, -1.0f, -0.5f, 0.5f, 1.0f, 0.5f, -0.5f, 0.5f, -0.5f};

// Transpose one plane (C,H,W) -> (H,W,C). One thread per output element.
__global__ __launch_bounds__(256) void transpose_plane(const float* __restrict__ in,
                                                       float* __restrict__ outp) {
    int t = blockIdx.x * 256 + threadIdx.x;   // t < 32*256*256
    int c = t & 31;
    int x = (t >> 5) & 255;
    int y = t >> 13;
    outp[t] = in[c * (RES * RES) + y * RES + x];
}

__device__ inline unsigned spread3(unsigned v) {   // 5 bits -> every 3rd bit
    unsigned r = 0;
    r |= (v & 1u);
    r |= (v & 2u) << 2;
    r |= (v & 4u) << 4;
    r |= (v & 8u) << 6;
    r |= (v & 16u) << 8;
    return r;
}

__device__ inline unsigned morton_key(const float* __restrict__ pts,
                                      const float* __restrict__ aabb, int i) {
    float a00 = aabb[0], a01 = aabb[1], a02 = aabb[2];
    float a10 = aabb[3], a11 = aabb[4], a12 = aabb[5];
    float s0 = 2.0f / (a10 - a00);
    float s1 = 2.0f / (a11 - a01);
    float s2 = 2.0f / (a12 - a02);
    float px = (pts[i * 3 + 0] - a00) * s0 - 1.0f;   // in ~[-0.9, 0.9]
    float py = (pts[i * 3 + 1] - a01) * s1 - 1.0f;
    float pz = (pts[i * 3 + 2] - a02) * s2 - 1.0f;
    unsigned ux = (unsigned)min(max((int)((px + 1.0f) * 16.0f), 0), 31);
    unsigned uy = (unsigned)min(max((int)((py + 1.0f) * 16.0f), 0), 31);
    unsigned uz = (unsigned)min(max((int)((pz + 1.0f) * 16.0f), 0), 31);
    return spread3(ux) | (spread3(uy) << 1) | (spread3(uz) << 2);
}

__global__ __launch_bounds__(256) void build_hist(const float* __restrict__ pts,
                                                  const float* __restrict__ aabb,
                                                  int* __restrict__ hist, int n) {
    int i = blockIdx.x * 256 + threadIdx.x;
    if (i >= n) return;
    atomicAdd(&hist[morton_key(pts, aabb, i)], 1);
}

// Exclusive prefix sum over NBINS bins. One block of 1024 threads, 32 bins each.
__global__ __launch_bounds__(1024) void scan_hist(int* __restrict__ hist) {
    __shared__ int sums[1024];
    int t = threadIdx.x;
    int base = t * 32;
    int local[32];
    int s = 0;
#pragma unroll
    for (int i = 0; i < 32; ++i) { local[i] = hist[base + i]; s += local[i]; }
    sums[t] = s;
    __syncthreads();
    for (int off = 1; off < 1024; off <<= 1) {
        int v = 0;
        if (t >= off) v = sums[t - off];
        __syncthreads();
        if (t >= off) sums[t] += v;
        __syncthreads();
    }
    int excl = (t == 0) ? 0 : sums[t - 1];
#pragma unroll
    for (int i = 0; i < 32; ++i) { hist[base + i] = excl; excl += local[i]; }
}

__global__ __launch_bounds__(256) void scatter_sorted(const float* __restrict__ pts,
                                                      const float* __restrict__ scales,
                                                      const float* __restrict__ aabb,
                                                      int* __restrict__ hist,
                                                      float* __restrict__ pts_s,
                                                      float* __restrict__ scales_s,
                                                      int* __restrict__ idx_s, int n) {
    int i = blockIdx.x * 256 + threadIdx.x;
    if (i >= n) return;
    unsigned key = morton_key(pts, aabb, i);
    int pos = atomicAdd(&hist[key], 1);
    pts_s[pos * 3 + 0] = pts[i * 3 + 0];
    pts_s[pos * 3 + 1] = pts[i * 3 + 1];
    pts_s[pos * 3 + 2] = pts[i * 3 + 2];
    scales_s[pos * 3 + 0] = scales[i * 3 + 0];
    scales_s[pos * 3 + 1] = scales[i * 3 + 1];
    scales_s[pos * 3 + 2] = scales[i * 3 + 2];
    idx_s[pos] = i;
}

__device__ inline float4 fetch_corner_t(const float* __restrict__ plane, int y, int x, int cg) {
    const float4* p = reinterpret_cast<const float4*>(plane + ((size_t)(y * RES + x) << 5));
    return p[cg];
}

__device__ inline void accum_pair_t(float4& interp, const float* __restrict__ plane,
                                    float bx, float by, float sx, float sy, int cg) {
    float4 featsum = make_float4(0.f, 0.f, 0.f, 0.f);
#pragma unroll
    for (int s = 0; s < 13; ++s) {
        float pxn = bx + sx * c_offx[s];
        float pyn = by + sy * c_offy[s];
        float x = fminf(fmaxf((pxn + 1.0f) * 0.5f * 255.0f, 0.0f), 255.0f);
        float y = fminf(fmaxf((pyn + 1.0f) * 0.5f * 255.0f, 0.0f), 255.0f);
        float x0f = floorf(x);
        float y0f = floorf(y);
        float wx = x - x0f;
        float wy = y - y0f;
        int x0 = (int)x0f;
        int y0 = (int)y0f;
        int x1 = min(x0 + 1, RES - 1);
        int y1 = min(y0 + 1, RES - 1);
        float w00 = (1.0f - wx) * (1.0f - wy);
        float w10 = wx * (1.0f - wy);
        float w01 = (1.0f - wx) * wy;
        float w11 = wx * wy;
        float4 f00 = fetch_corner_t(plane, y0, x0, cg);
        float4 f10 = fetch_corner_t(plane, y0, x1, cg);
        float4 f01 = fetch_corner_t(plane, y1, x0, cg);
        float4 f11 = fetch_corner_t(plane, y1, x1, cg);
        featsum.x = fmaf(f00.x, w00, fmaf(f10.x, w10, fmaf(f01.x, w01, fmaf(f11.x, w11, featsum.x))));
        featsum.y = fmaf(f00.y, w00, fmaf(f10.y, w10, fmaf(f01.y, w01, fmaf(f11.y, w11, featsum.y))));
        featsum.z = fmaf(f00.z, w00, fmaf(f10.z, w10, fmaf(f01.z, w01, fmaf(f11.z, w11, featsum.z))));
        featsum.w = fmaf(f00.w, w00, fmaf(f10.w, w10, fmaf(f01.w, w01, fmaf(f11.w, w11, featsum.w))));
    }
    const float inv13 = 1.0f / 13.0f;
    interp.x *= featsum.x * inv13;
    interp.y *= featsum.y * inv13;
    interp.z *= featsum.z * inv13;
    interp.w *= featsum.w * inv13;
}

// Main kernel over SORTED points. 8 lanes per point (4 channels each).
__global__ __launch_bounds__(256) void wpf_sorted(const float* __restrict__ pts_s,
                                                  const float* __restrict__ scales_s,
                                                  const int* __restrict__ idx_s,
                                                  const float* __restrict__ p0,
                                                  const float* __restrict__ p1,
                                                  const float* __restrict__ p2,
                                                  const float* __restrict__ aabb,
                                                  float* __restrict__ out, int n, int swizzle) {
    int b = blockIdx.x;
    if (swizzle) {
        int nb = gridDim.x;
        int chunk = nb >> 3;                 // contiguous Morton range per XCD
        b = (b & 7) * chunk + (b >> 3);
    }
    int t = b * 256 + threadIdx.x;
    int pt = t >> 3;
    int cg = t & 7;
    if (pt >= n) return;

    float a00 = aabb[0], a01 = aabb[1], a02 = aabb[2];
    float a10 = aabb[3], a11 = aabb[4], a12 = aabb[5];
    float s0 = 2.0f / (a10 - a00);
    float s1 = 2.0f / (a11 - a01);
    float s2 = 2.0f / (a12 - a02);

    float px = (pts_s[pt * 3 + 0] - a00) * s0 - 1.0f;
    float py = (pts_s[pt * 3 + 1] - a01) * s1 - 1.0f;
    float pz = (pts_s[pt * 3 + 2] - a02) * s2 - 1.0f;

    float scx = scales_s[pt * 3 + 0];
    float scy = scales_s[pt * 3 + 1];
    float scz = scales_s[pt * 3 + 2];

    float4 interp = make_float4(1.f, 1.f, 1.f, 1.f);
    accum_pair_t(interp, p0, px, py, scx, scy, cg);   // pair (0,1)
    accum_pair_t(interp, p1, px, pz, scx, scz, cg);   // pair (0,2)
    accum_pair_t(interp, p2, py, pz, scy, scz, cg);   // pair (1,2)

    int oi = idx_s[pt];
    reinterpret_cast<float4*>(out)[(size_t)oi * 8 + cg] = interp;
}

// --- fallback (no sort): previous round's kernel ---
__global__ __launch_bounds__(256) void wpf_plain(const float* __restrict__ pts,
                                                 const float* __restrict__ scales,
                                                 const float* __restrict__ p0,
                                                 const float* __restrict__ p1,
                                                 const float* __restrict__ p2,
                                                 const float* __restrict__ aabb,
                                                 float* __restrict__ out, int n, int transposed) {
    int t = blockIdx.x * 256 + threadIdx.x;
    int pt = t >> 3;
    int cg = t & 7;
    if (pt >= n) return;
    float a00 = aabb[0], a01 = aabb[1], a02 = aabb[2];
    float a10 = aabb[3], a11 = aabb[4], a12 = aabb[5];
    float s0 = 2.0f / (a10 - a00);
    float s1 = 2.0f / (a11 - a01);
    float s2 = 2.0f / (a12 - a02);
    float px = (pts[pt * 3 + 0] - a00) * s0 - 1.0f;
    float py = (pts[pt * 3 + 1] - a01) * s1 - 1.0f;
    float pz = (pts[pt * 3 + 2] - a02) * s2 - 1.0f;
    float scx = scales[pt * 3 + 0];
    float scy = scales[pt * 3 + 1];
    float scz = scales[pt * 3 + 2];
    float4 interp = make_float4(1.f, 1.f, 1.f, 1.f);
    if (transposed) {
        accum_pair_t(interp, p0, px, py, scx, scy, cg);
        accum_pair_t(interp, p1, px, pz, scx, scz, cg);
        accum_pair_t(interp, p2, py, pz, scy, scz, cg);
    } else {
        // strided (C,H,W) gather — worst case, only if ws too small
        for (int pair = 0; pair < 3; ++pair) {
            const float* plane = pair == 0 ? p0 : (pair == 1 ? p1 : p2);
            float bx = pair == 0 ? px : (pair == 1 ? px : py);
            float by = pair == 0 ? py : (pair == 1 ? pz : pz);
            float sx = pair == 0 ? scx : (pair == 1 ? scx : scy);
            float sy = pair == 0 ? scy : (pair == 1 ? scz : scz);
            float4 featsum = make_float4(0.f, 0.f, 0.f, 0.f);
            for (int s = 0; s < 13; ++s) {
                float pxn = bx + sx * c_offx[s];
                float pyn = by + sy * c_offy[s];
                float x = fminf(fmaxf((pxn + 1.0f) * 0.5f * 255.0f, 0.0f), 255.0f);
                float y = fminf(fmaxf((pyn + 1.0f) * 0.5f * 255.0f, 0.0f), 255.0f);
                float x0f = floorf(x), y0f = floorf(y);
                float wx = x - x0f, wy = y - y0f;
                int x0 = (int)x0f, y0 = (int)y0f;
                int x1 = min(x0 + 1, RES - 1), y1 = min(y0 + 1, RES - 1);
                float w00 = (1.0f - wx) * (1.0f - wy);
                float w10 = wx * (1.0f - wy);
                float w01 = (1.0f - wx) * wy;
                float w11 = wx * wy;
                int c0 = cg << 2;
                for (int c = 0; c < 4; ++c) {
                    const float* pl = plane + (size_t)(c0 + c) * (RES * RES);
                    float f = pl[y0 * RES + x0] * w00 + pl[y0 * RES + x1] * w10 +
                              pl[y1 * RES + x0] * w01 + pl[y1 * RES + x1] * w11;
                    (&featsum.x)[c] += f;
                }
            }
            const float inv13 = 1.0f / 13.0f;
            interp.x *= featsum.x * inv13;
            interp.y *= featsum.y * inv13;
            interp.z *= featsum.z * inv13;
            interp.w *= featsum.w * inv13;
        }
    }
    reinterpret_cast<float4*>(out)[(size_t)pt * 8 + cg] = interp;
}

extern "C" void kernel_launch(void* const* d_in, const int* in_sizes, int n_in,
                              void* d_out, int out_size, void* d_ws, size_t ws_size,
                              hipStream_t stream) {
    const float* pts    = (const float*)d_in[0];
    const float* scales = (const float*)d_in[2];
    const float* p0     = (const float*)d_in[3];
    const float* p1     = (const float*)d_in[4];
    const float* p2     = (const float*)d_in[5];
    const float* aabb   = (const float*)d_in[6];
    float* out = (float*)d_out;

    int n = in_sizes[0] / 3;
    int main_blocks = (n * 8 + 255) / 256;
    int pt_blocks = (n + 255) / 256;

    size_t planes_bytes = (size_t)3 * PLANE_ELEMS * sizeof(float);
    size_t sort_bytes = (size_t)n * 3 * sizeof(float) * 2   // pts_s + scales_s
                      + (size_t)n * sizeof(int)             // idx_s
                      + (size_t)NBINS * sizeof(int);        // hist
    bool have_planes = ws_size >= planes_bytes;
    bool have_sort = ws_size >= planes_bytes + sort_bytes;

    if (have_planes) {
        float* w0 = (float*)d_ws;
        float* w1 = w0 + PLANE_ELEMS;
        float* w2 = w1 + PLANE_ELEMS;
        int tb = PLANE_ELEMS / 256;
        transpose_plane<<<tb, 256, 0, stream>>>(p0, w0);
        transpose_plane<<<tb, 256, 0, stream>>>(p1, w1);
        transpose_plane<<<tb, 256, 0, stream>>>(p2, w2);

        if (have_sort) {
            float* pts_s    = w2 + PLANE_ELEMS;
            float* scales_s = pts_s + (size_t)n * 3;
            int*   idx_s    = (int*)(scales_s + (size_t)n * 3);
            int*   hist     = idx_s + n;

            hipMemsetAsync(hist, 0, NBINS * sizeof(int), stream);
            build_hist<<<pt_blocks, 256, 0, stream>>>(pts, aabb, hist, n);
            scan_hist<<<1, 1024, 0, stream>>>(hist);
            scatter_sorted<<<pt_blocks, 256, 0, stream>>>(pts, scales, aabb, hist,
                                                          pts_s, scales_s, idx_s, n);
            int swizzle = (main_blocks % 8 == 0) ? 1 : 0;
            wpf_sorted<<<main_blocks, 256, 0, stream>>>(pts_s, scales_s, idx_s,
                                                        w0, w1, w2, aabb, out, n, swizzle);
        } else {
            wpf_plain<<<main_blocks, 256, 0, stream>>>(pts, scales, w0, w1, w2, aabb, out, n, 1);
        }
    } else {
        wpf_plain<<<main_blocks, 256, 0, stream>>>(pts, scales, p0, p1, p2, aabb, out, n, 0);
    }
}

// Round 3
// 374.862 us; speedup vs baseline: 2.4585x; 1.3536x over previous
//
#include <hip/hip_runtime.h>
#include <hip/hip_fp16.h>

#define RES 256
#define FEAT 32
#define PLANE_ELEMS (FEAT * RES * RES)   // 2097152, fp16 plane = 4 MB
#define NBINS 32768                      // 32^3 Morton bins

// ---------------- preprocessing ----------------

// Transpose+quantize all 3 planes (C,H,W) fp32 -> (H,W,C) fp16, one kernel.
__global__ __launch_bounds__(256) void transpose_quant(const float* __restrict__ p0,
                                                       const float* __restrict__ p1,
                                                       const float* __restrict__ p2,
                                                       __half* __restrict__ outp) {
    int t = blockIdx.x * 256 + threadIdx.x;          // t < 3 * 2097152
    int pl = t >> 21;
    int r = t & (PLANE_ELEMS - 1);
    int c = r & 31;
    int x = (r >> 5) & 255;
    int y = r >> 13;
    const float* in = pl == 0 ? p0 : (pl == 1 ? p1 : p2);
    outp[t] = __float2half(in[c * (RES * RES) + y * RES + x]);
}

__device__ inline unsigned spread3(unsigned v) {
    unsigned r = 0;
    r |= (v & 1u);
    r |= (v & 2u) << 2;
    r |= (v & 4u) << 4;
    r |= (v & 8u) << 6;
    r |= (v & 16u) << 8;
    return r;
}

__global__ __launch_bounds__(256) void build_hist_keys(const float* __restrict__ pts,
                                                       const float* __restrict__ aabb,
                                                       int* __restrict__ hist,
                                                       int* __restrict__ keys, int n) {
    int i = blockIdx.x * 256 + threadIdx.x;
    if (i >= n) return;
    float a00 = aabb[0], a01 = aabb[1], a02 = aabb[2];
    float a10 = aabb[3], a11 = aabb[4], a12 = aabb[5];
    float px = (pts[i * 3 + 0] - a00) * (2.0f / (a10 - a00)) - 1.0f;
    float py = (pts[i * 3 + 1] - a01) * (2.0f / (a11 - a01)) - 1.0f;
    float pz = (pts[i * 3 + 2] - a02) * (2.0f / (a12 - a02)) - 1.0f;
    unsigned ux = (unsigned)min(max((int)((px + 1.0f) * 16.0f), 0), 31);
    unsigned uy = (unsigned)min(max((int)((py + 1.0f) * 16.0f), 0), 31);
    unsigned uz = (unsigned)min(max((int)((pz + 1.0f) * 16.0f), 0), 31);
    int key = (int)(spread3(ux) | (spread3(uy) << 1) | (spread3(uz) << 2));
    keys[i] = key;
    atomicAdd(&hist[key], 1);
}

__global__ __launch_bounds__(1024) void scan_hist(int* __restrict__ hist) {
    __shared__ int sums[1024];
    int t = threadIdx.x;
    int base = t * 32;
    int local[32];
    int s = 0;
#pragma unroll
    for (int i = 0; i < 32; ++i) { local[i] = hist[base + i]; s += local[i]; }
    sums[t] = s;
    __syncthreads();
    for (int off = 1; off < 1024; off <<= 1) {
        int v = 0;
        if (t >= off) v = sums[t - off];
        __syncthreads();
        if (t >= off) sums[t] += v;
        __syncthreads();
    }
    int excl = (t == 0) ? 0 : sums[t - 1];
#pragma unroll
    for (int i = 0; i < 32; ++i) { hist[base + i] = excl; excl += local[i]; }
}

// Scatter sorted, pre-transformed records: [cx,cy,cz,0, hx,hy,hz,0] in pixel units.
// cx = (pxn+1)*127.5 ; hx = sx*63.75 (half-step: sample x = cx + (k-2)*hx, k=0..4)
__global__ __launch_bounds__(256) void scatter_pack(const float* __restrict__ pts,
                                                    const float* __restrict__ scales,
                                                    const float* __restrict__ aabb,
                                                    const int* __restrict__ keys,
                                                    int* __restrict__ hist,
                                                    float* __restrict__ ppk,
                                                    int* __restrict__ idx_s, int n) {
    int i = blockIdx.x * 256 + threadIdx.x;
    if (i >= n) return;
    float a00 = aabb[0], a01 = aabb[1], a02 = aabb[2];
    float a10 = aabb[3], a11 = aabb[4], a12 = aabb[5];
    float px = (pts[i * 3 + 0] - a00) * (2.0f / (a10 - a00)) - 1.0f;
    float py = (pts[i * 3 + 1] - a01) * (2.0f / (a11 - a01)) - 1.0f;
    float pz = (pts[i * 3 + 2] - a02) * (2.0f / (a12 - a02)) - 1.0f;
    int pos = atomicAdd(&hist[keys[i]], 1);
    float4* o = reinterpret_cast<float4*>(ppk) + (size_t)pos * 2;
    o[0] = make_float4((px + 1.0f) * 127.5f, (py + 1.0f) * 127.5f, (pz + 1.0f) * 127.5f, 0.0f);
    o[1] = make_float4(scales[i * 3 + 0] * 63.75f, scales[i * 3 + 1] * 63.75f,
                       scales[i * 3 + 2] * 63.75f, 0.0f);
    idx_s[pos] = i;
}

// ---------------- main kernel ----------------

__device__ inline void corner_fma(float fs[8], const char* __restrict__ p, float w) {
    float4 raw = *reinterpret_cast<const float4*>(p);   // 8 halves
    const __half2* h = reinterpret_cast<const __half2*>(&raw);
#pragma unroll
    for (int c = 0; c < 4; ++c) {
        float2 f = __half22float2(h[c]);
        fs[2 * c]     = fmaf(f.x, w, fs[2 * c]);
        fs[2 * c + 1] = fmaf(f.y, w, fs[2 * c + 1]);
    }
}

__device__ inline void pair_accum(float interp[8], const __half* __restrict__ plane,
                                  float cx, float cy, float hx, float hy, int cg) {
    // 13 samples on a 5x5 grid: index tables (i -> x slot, j -> y slot)
    const int SI[13] = {2, 0, 1, 3, 4, 2, 2, 2, 2, 3, 3, 1, 1};
    const int SJ[13] = {2, 2, 2, 2, 2, 0, 1, 3, 4, 3, 1, 3, 1};

    float wx[5], wxc[5], wy[5], wyc[5];
    int colA[5], colB[5], rowA[5], rowB[5];
    int chan = cg * 16;                 // byte offset of this lane's 8 channels
#pragma unroll
    for (int k = 0; k < 5; ++k) {
        float x = fminf(fmaxf(cx + (float)(k - 2) * hx, 0.0f), 255.0f);
        float xf = floorf(x);
        int x0 = (int)xf;
        int x1 = min(x0 + 1, 255);
        wx[k] = x - xf; wxc[k] = 1.0f - wx[k];
        colA[k] = x0 * 64 + chan;       // texel = 32ch * 2B = 64 B
        colB[k] = x1 * 64 + chan;
        float y = fminf(fmaxf(cy + (float)(k - 2) * hy, 0.0f), 255.0f);
        float yf = floorf(y);
        int y0 = (int)yf;
        int y1 = min(y0 + 1, 255);
        wy[k] = y - yf; wyc[k] = 1.0f - wy[k];
        rowA[k] = y0 * (RES * 64);
        rowB[k] = y1 * (RES * 64);
    }

    float fs[8] = {0, 0, 0, 0, 0, 0, 0, 0};
    const char* base = reinterpret_cast<const char*>(plane);
#pragma unroll
    for (int s = 0; s < 13; ++s) {
        int i = SI[s], j = SJ[s];
        float w00 = wxc[i] * wyc[j];
        float w10 = wx[i] * wyc[j];
        float w01 = wxc[i] * wy[j];
        float w11 = wx[i] * wy[j];
        corner_fma(fs, base + (rowA[j] + colA[i]), w00);
        corner_fma(fs, base + (rowA[j] + colB[i]), w10);
        corner_fma(fs, base + (rowB[j] + colA[i]), w01);
        corner_fma(fs, base + (rowB[j] + colB[i]), w11);
    }
    const float inv13 = 1.0f / 13.0f;
#pragma unroll
    for (int c = 0; c < 8; ++c) interp[c] *= fs[c] * inv13;
}

// 4 lanes per point, 8 channels per lane.
__global__ __launch_bounds__(256) void wpf_main4(const float* __restrict__ ppk,
                                                 const int* __restrict__ idx_s,
                                                 const __half* __restrict__ planes, // 3 concat
                                                 float* __restrict__ out, int n, int swizzle) {
    int b = blockIdx.x;
    if (swizzle) {
        int nb = gridDim.x;
        int chunk = nb >> 3;
        b = (b & 7) * chunk + (b >> 3);
    }
    int t = b * 256 + threadIdx.x;
    int pt = t >> 2;
    int cg = t & 3;
    if (pt >= n) return;

    float4 a  = reinterpret_cast<const float4*>(ppk)[(size_t)pt * 2];
    float4 hh = reinterpret_cast<const float4*>(ppk)[(size_t)pt * 2 + 1];

    float interp[8] = {1, 1, 1, 1, 1, 1, 1, 1};
#pragma unroll 1
    for (int pr = 0; pr < 3; ++pr) {
        const __half* pl = planes + (size_t)pr * PLANE_ELEMS;
        float cx = (pr == 2) ? a.y : a.x;
        float cy = (pr == 0) ? a.y : a.z;
        float hx = (pr == 2) ? hh.y : hh.x;
        float hy = (pr == 0) ? hh.y : hh.z;
        pair_accum(interp, pl, cx, cy, hx, hy, cg);
    }

    int oi = idx_s[pt];
    float4* o = reinterpret_cast<float4*>(out + (size_t)oi * 32 + cg * 8);
    o[0] = make_float4(interp[0], interp[1], interp[2], interp[3]);
    o[1] = make_float4(interp[4], interp[5], interp[6], interp[7]);
}

// ---------------- fallback (ws too small): direct fp32 strided path ----------------
__global__ __launch_bounds__(256) void wpf_plain(const float* __restrict__ pts,
                                                 const float* __restrict__ scales,
                                                 const float* __restrict__ p0,
                                                 const float* __restrict__ p1,
                                                 const float* __restrict__ p2,
                                                 const float* __restrict__ aabb,
                                                 float* __restrict__ out, int n) {
    const float offx[13] = {0.f, -1.f, -0.5f, 0.5f, 1.f, 0.f, 0.f, 0.f, 0.f, 0.5f, 0.5f, -0.5f, -0.5f};
    const float offy[13] = {0.f, 0.f, 0.f, 0.f, 0.f, -1.f, -0.5f, 0.5f, 1.f, 0.5f, -0.5f, 0.5f, -0.5f};
    int t = blockIdx.x * 256 + threadIdx.x;
    int pt = t >> 3;
    int cg = t & 7;
    if (pt >= n) return;
    float a00 = aabb[0], a01 = aabb[1], a02 = aabb[2];
    float a10 = aabb[3], a11 = aabb[4], a12 = aabb[5];
    float px = (pts[pt * 3 + 0] - a00) * (2.0f / (a10 - a00)) - 1.0f;
    float py = (pts[pt * 3 + 1] - a01) * (2.0f / (a11 - a01)) - 1.0f;
    float pz = (pts[pt * 3 + 2] - a02) * (2.0f / (a12 - a02)) - 1.0f;
    float scx = scales[pt * 3 + 0], scy = scales[pt * 3 + 1], scz = scales[pt * 3 + 2];
    float4 interp = make_float4(1.f, 1.f, 1.f, 1.f);
    for (int pair = 0; pair < 3; ++pair) {
        const float* plane = pair == 0 ? p0 : (pair == 1 ? p1 : p2);
        float bx = pair == 2 ? py : px;
        float by = pair == 0 ? py : pz;
        float sx = pair == 2 ? scy : scx;
        float sy = pair == 0 ? scy : scz;
        float4 featsum = make_float4(0.f, 0.f, 0.f, 0.f);
        for (int s = 0; s < 13; ++s) {
            float x = fminf(fmaxf((bx + sx * offx[s] + 1.0f) * 127.5f, 0.0f), 255.0f);
            float y = fminf(fmaxf((by + sy * offy[s] + 1.0f) * 127.5f, 0.0f), 255.0f);
            float x0f = floorf(x), y0f = floorf(y);
            float wx = x - x0f, wy = y - y0f;
            int x0 = (int)x0f, y0 = (int)y0f;
            int x1 = min(x0 + 1, RES - 1), y1 = min(y0 + 1, RES - 1);
            float w00 = (1.0f - wx) * (1.0f - wy), w10 = wx * (1.0f - wy);
            float w01 = (1.0f - wx) * wy, w11 = wx * wy;
            int c0 = cg << 2;
            for (int c = 0; c < 4; ++c) {
                const float* pl = plane + (size_t)(c0 + c) * (RES * RES);
                float f = pl[y0 * RES + x0] * w00 + pl[y0 * RES + x1] * w10 +
                          pl[y1 * RES + x0] * w01 + pl[y1 * RES + x1] * w11;
                (&featsum.x)[c] += f;
            }
        }
        const float inv13 = 1.0f / 13.0f;
        interp.x *= featsum.x * inv13;
        interp.y *= featsum.y * inv13;
        interp.z *= featsum.z * inv13;
        interp.w *= featsum.w * inv13;
    }
    reinterpret_cast<float4*>(out)[(size_t)pt * 8 + cg] = interp;
}

extern "C" void kernel_launch(void* const* d_in, const int* in_sizes, int n_in,
                              void* d_out, int out_size, void* d_ws, size_t ws_size,
                              hipStream_t stream) {
    const float* pts    = (const float*)d_in[0];
    const float* scales = (const float*)d_in[2];
    const float* p0     = (const float*)d_in[3];
    const float* p1     = (const float*)d_in[4];
    const float* p2     = (const float*)d_in[5];
    const float* aabb   = (const float*)d_in[6];
    float* out = (float*)d_out;

    int n = in_sizes[0] / 3;
    int pt_blocks = (n + 255) / 256;

    // workspace layout
    size_t planes_hbytes = (size_t)3 * PLANE_ELEMS * sizeof(__half);  // 12 MB
    size_t ppk_bytes = (size_t)n * 8 * sizeof(float);                 // 16 MB
    size_t idx_bytes = (size_t)n * sizeof(int);                       // 2 MB
    size_t key_bytes = (size_t)n * sizeof(int);                       // 2 MB
    size_t hist_bytes = (size_t)NBINS * sizeof(int);
    size_t need = planes_hbytes + ppk_bytes + idx_bytes + key_bytes + hist_bytes;

    if (ws_size >= need) {
        __half* planes_h = (__half*)d_ws;
        float*  ppk   = (float*)((char*)d_ws + planes_hbytes);
        int*    idx_s = (int*)((char*)ppk + ppk_bytes);
        int*    keys  = idx_s + n;
        int*    hist  = keys + n;

        transpose_quant<<<(3 * PLANE_ELEMS) / 256, 256, 0, stream>>>(p0, p1, p2, planes_h);
        hipMemsetAsync(hist, 0, hist_bytes, stream);
        build_hist_keys<<<pt_blocks, 256, 0, stream>>>(pts, aabb, hist, keys, n);
        scan_hist<<<1, 1024, 0, stream>>>(hist);
        scatter_pack<<<pt_blocks, 256, 0, stream>>>(pts, scales, aabb, keys, hist,
                                                    ppk, idx_s, n);
        int main_blocks = (n * 4 + 255) / 256;
        int swizzle = (main_blocks % 8 == 0) ? 1 : 0;
        wpf_main4<<<main_blocks, 256, 0, stream>>>(ppk, idx_s, planes_h, out, n, swizzle);
    } else {
        int main_blocks = (n * 8 + 255) / 256;
        wpf_plain<<<main_blocks, 256, 0, stream>>>(pts, scales, p0, p1, p2, aabb, out, n);
    }
}